// Round 4
// baseline (1876.956 us; speedup 1.0000x reference)
//
#include <hip/hip_runtime.h>

#define N_NODES 100000
#define N_EDGES 1600000
#define N_FEAT  256
#define N_HID   64
#define N_CLS   16

// ---------------------------------------------------------------------------
// GEMM1: h0[100000][64] = x[100000][256] @ W1[256][64] + b1  (all fp32)
// Block: 64 nodes x 64 cols, 256 threads, 4x4 accum per thread, BK=16.
// ---------------------------------------------------------------------------
__global__ __launch_bounds__(256) void gemm1_k(const float* __restrict__ x,
                                               const float* __restrict__ W1,
                                               const float* __restrict__ b1,
                                               float* __restrict__ h0) {
    __shared__ float As[16][64];   // [k][m]
    __shared__ float Bs[16][64];   // [k][n]
    const int bm  = blockIdx.x * 64;
    const int tid = threadIdx.x;
    const int tx = tid & 15;       // n/4
    const int ty = tid >> 4;       // m/4
    // A loader: 64 rows x 16 k, one float4 per thread
    const int a_row = tid >> 2;
    const int a_k   = (tid & 3) * 4;
    // B loader: 16 k x 64 n, one float4 per thread
    const int b_k = tid >> 4;
    const int b_n = (tid & 15) * 4;

    const int  arow_g = bm + a_row;
    const bool a_ok   = arow_g < N_NODES;

    float acc[4][4] = {};

    for (int k0 = 0; k0 < N_FEAT; k0 += 16) {
        float4 ar = make_float4(0.f, 0.f, 0.f, 0.f);
        if (a_ok) ar = *(const float4*)(x + (size_t)arow_g * N_FEAT + k0 + a_k);
        float4 br = *(const float4*)(W1 + (size_t)(k0 + b_k) * N_HID + b_n);

        As[a_k + 0][a_row] = ar.x;
        As[a_k + 1][a_row] = ar.y;
        As[a_k + 2][a_row] = ar.z;
        As[a_k + 3][a_row] = ar.w;
        *(float4*)&Bs[b_k][b_n] = br;
        __syncthreads();

        #pragma unroll
        for (int kk = 0; kk < 16; ++kk) {
            float4 av = *(const float4*)&As[kk][ty * 4];
            float4 bv = *(const float4*)&Bs[kk][tx * 4];
            float a[4] = {av.x, av.y, av.z, av.w};
            float b[4] = {bv.x, bv.y, bv.z, bv.w};
            #pragma unroll
            for (int i = 0; i < 4; ++i)
                #pragma unroll
                for (int j = 0; j < 4; ++j)
                    acc[i][j] += a[i] * b[j];
        }
        __syncthreads();
    }

    float bb[4];
    #pragma unroll
    for (int j = 0; j < 4; ++j) bb[j] = b1[tx * 4 + j];

    #pragma unroll
    for (int i = 0; i < 4; ++i) {
        int row = bm + ty * 4 + i;
        if (row < N_NODES) {
            float4 o;
            o.x = acc[i][0] + bb[0];
            o.y = acc[i][1] + bb[1];
            o.z = acc[i][2] + bb[2];
            o.w = acc[i][3] + bb[3];
            *(float4*)(h0 + (size_t)row * N_HID + tx * 4) = o;
        }
    }
}

// ---------------------------------------------------------------------------
// SpMM scatter: out[row[e]] += vals[e] * h[col[e]]  (fp32, HW atomics)
// One thread per (edge, float4-column). D = 4 << LOG_D4 features.
// ---------------------------------------------------------------------------
template <int LOG_D4>
__global__ __launch_bounds__(256) void spmm_k(const int* __restrict__ rowi,
                                              const int* __restrict__ coli,
                                              const float* __restrict__ vals,
                                              const float* __restrict__ h,
                                              float* __restrict__ outp) {
    const int D4 = 1 << LOG_D4;
    const int D  = D4 * 4;
    int tid = blockIdx.x * 256 + threadIdx.x;
    const int total = N_EDGES << LOG_D4;
    if (tid >= total) return;
    int e = tid >> LOG_D4;
    int c = tid & (D4 - 1);
    int cc = coli[e];
    int rr = rowi[e];
    float v = vals[e];
    float4 hv = *(const float4*)(h + (size_t)cc * D + c * 4);
    float* op = outp + (size_t)rr * D + c * 4;
    unsafeAtomicAdd(op + 0, v * hv.x);
    unsafeAtomicAdd(op + 1, v * hv.y);
    unsafeAtomicAdd(op + 2, v * hv.z);
    unsafeAtomicAdd(op + 3, v * hv.w);
}

// ---------------------------------------------------------------------------
// GEMM2 fused with ReLU: h2[100000][16] = relu(h1)[100000][64] @ W2[64][16] + b2
// Block: 64 nodes, 256 threads (4 threads/node, 4 cols each).
// ---------------------------------------------------------------------------
__global__ __launch_bounds__(256) void gemm2_k(const float* __restrict__ h1,
                                               const float* __restrict__ W2,
                                               const float* __restrict__ b2,
                                               float* __restrict__ h2) {
    __shared__ float Hs[64][65];   // padded
    __shared__ float Ws[64 * 16];
    __shared__ float bs[16];
    const int bn  = blockIdx.x * 64;
    const int tid = threadIdx.x;

    {   // W2: 1024 floats, one float4 per thread
        *(float4*)&Ws[tid * 4] = *(const float4*)(W2 + tid * 4);
    }
    if (tid < 16) bs[tid] = b2[tid];

    #pragma unroll
    for (int i = 0; i < 4; ++i) {
        int idx  = tid + i * 256;     // float4 index into 64x64 tile
        int node = idx >> 4;
        int c4   = idx & 15;
        int nr   = bn + node;
        float4 hv = make_float4(0.f, 0.f, 0.f, 0.f);
        if (nr < N_NODES) hv = *(const float4*)(h1 + (size_t)nr * N_HID + c4 * 4);
        Hs[node][c4 * 4 + 0] = fmaxf(hv.x, 0.f);
        Hs[node][c4 * 4 + 1] = fmaxf(hv.y, 0.f);
        Hs[node][c4 * 4 + 2] = fmaxf(hv.z, 0.f);
        Hs[node][c4 * 4 + 3] = fmaxf(hv.w, 0.f);
    }
    __syncthreads();

    const int node = tid >> 2;
    const int c0   = (tid & 3) * 4;
    float a0 = bs[c0 + 0], a1 = bs[c0 + 1], a2 = bs[c0 + 2], a3 = bs[c0 + 3];
    #pragma unroll
    for (int k = 0; k < 64; ++k) {
        float hval = Hs[node][k];
        a0 += hval * Ws[k * 16 + c0 + 0];
        a1 += hval * Ws[k * 16 + c0 + 1];
        a2 += hval * Ws[k * 16 + c0 + 2];
        a3 += hval * Ws[k * 16 + c0 + 3];
    }
    int nr = bn + node;
    if (nr < N_NODES)
        *(float4*)(h2 + (size_t)nr * N_CLS + c0) = make_float4(a0, a1, a2, a3);
}

// ---------------------------------------------------------------------------
// log_softmax over 16 classes; fp32 in, fp32 out. One thread per node.
// ---------------------------------------------------------------------------
__global__ __launch_bounds__(256) void lsm_k(const float* __restrict__ acc,
                                             float* __restrict__ outp) {
    int n = blockIdx.x * 256 + threadIdx.x;
    if (n >= N_NODES) return;
    float v[16];
    #pragma unroll
    for (int i = 0; i < 4; ++i) {
        float4 r = *(const float4*)(acc + (size_t)n * N_CLS + i * 4);
        v[i * 4 + 0] = r.x; v[i * 4 + 1] = r.y; v[i * 4 + 2] = r.z; v[i * 4 + 3] = r.w;
    }
    float m = v[0];
    #pragma unroll
    for (int i = 1; i < 16; ++i) m = fmaxf(m, v[i]);
    float s = 0.f;
    #pragma unroll
    for (int i = 0; i < 16; ++i) s += expf(v[i] - m);
    float lse = m + logf(s);
    float* o = outp + (size_t)n * N_CLS;
    #pragma unroll
    for (int i = 0; i < 4; ++i) {
        float4 r;
        r.x = v[i * 4 + 0] - lse;
        r.y = v[i * 4 + 1] - lse;
        r.z = v[i * 4 + 2] - lse;
        r.w = v[i * 4 + 3] - lse;
        *(float4*)(o + i * 4) = r;
    }
}

extern "C" void kernel_launch(void* const* d_in, const int* in_sizes, int n_in,
                              void* d_out, int out_size, void* d_ws, size_t ws_size,
                              hipStream_t stream) {
    const float* x        = (const float*)d_in[0];
    const int*   adj_row  = (const int*)d_in[1];
    const int*   adj_col  = (const int*)d_in[2];
    const float* adj_vals = (const float*)d_in[3];
    const float* W1       = (const float*)d_in[4];
    const float* b1       = (const float*)d_in[5];
    const float* W2       = (const float*)d_in[6];
    const float* b2       = (const float*)d_in[7];
    float*       out      = (float*)d_out;

    float* f    = (float*)d_ws;
    float* h0   = f;                                  // [100000*64] fp32
    float* h1   = f + (size_t)N_NODES * N_HID;        // [100000*64] fp32
    float* h2   = f;                                  // reuse h0 region: [100000*16]
    float* oacc = f + (size_t)N_NODES * N_CLS;        // reuse h0 region, after h2

    hipMemsetAsync(h1, 0, (size_t)N_NODES * N_HID * sizeof(float), stream);

    gemm1_k<<<(N_NODES + 63) / 64, 256, 0, stream>>>(x, W1, b1, h0);
    spmm_k<4><<<(N_EDGES * 16 + 255) / 256, 256, 0, stream>>>(adj_row, adj_col, adj_vals, h0, h1);
    hipMemsetAsync(oacc, 0, (size_t)N_NODES * N_CLS * sizeof(float), stream);
    gemm2_k<<<(N_NODES + 63) / 64, 256, 0, stream>>>(h1, W2, b2, h2);
    spmm_k<2><<<(N_EDGES * 4 + 255) / 256, 256, 0, stream>>>(adj_row, adj_col, adj_vals, h2, oacc);
    lsm_k<<<(N_NODES + 255) / 256, 256, 0, stream>>>(oacc, out);
}

// Round 5
// 471.620 us; speedup vs baseline: 3.9798x; 3.9798x over previous
//
#include <hip/hip_runtime.h>

#define N_NODES 100000
#define N_EDGES 1600000
#define N_FEAT  256
#define N_HID   64
#define N_CLS   16

// ---------------------------------------------------------------------------
// GEMM1: h0[100000][64] = x[100000][256] @ W1[256][64] + b1  (all fp32)
// ---------------------------------------------------------------------------
__global__ __launch_bounds__(256) void gemm1_k(const float* __restrict__ x,
                                               const float* __restrict__ W1,
                                               const float* __restrict__ b1,
                                               float* __restrict__ h0) {
    __shared__ float As[16][64];   // [k][m]
    __shared__ float Bs[16][64];   // [k][n]
    const int bm  = blockIdx.x * 64;
    const int tid = threadIdx.x;
    const int tx = tid & 15;       // n/4
    const int ty = tid >> 4;       // m/4
    const int a_row = tid >> 2;
    const int a_k   = (tid & 3) * 4;
    const int b_k = tid >> 4;
    const int b_n = (tid & 15) * 4;

    const int  arow_g = bm + a_row;
    const bool a_ok   = arow_g < N_NODES;

    float acc[4][4] = {};

    for (int k0 = 0; k0 < N_FEAT; k0 += 16) {
        float4 ar = make_float4(0.f, 0.f, 0.f, 0.f);
        if (a_ok) ar = *(const float4*)(x + (size_t)arow_g * N_FEAT + k0 + a_k);
        float4 br = *(const float4*)(W1 + (size_t)(k0 + b_k) * N_HID + b_n);

        As[a_k + 0][a_row] = ar.x;
        As[a_k + 1][a_row] = ar.y;
        As[a_k + 2][a_row] = ar.z;
        As[a_k + 3][a_row] = ar.w;
        *(float4*)&Bs[b_k][b_n] = br;
        __syncthreads();

        #pragma unroll
        for (int kk = 0; kk < 16; ++kk) {
            float4 av = *(const float4*)&As[kk][ty * 4];
            float4 bv = *(const float4*)&Bs[kk][tx * 4];
            float a[4] = {av.x, av.y, av.z, av.w};
            float b[4] = {bv.x, bv.y, bv.z, bv.w};
            #pragma unroll
            for (int i = 0; i < 4; ++i)
                #pragma unroll
                for (int j = 0; j < 4; ++j)
                    acc[i][j] += a[i] * b[j];
        }
        __syncthreads();
    }

    float bb[4];
    #pragma unroll
    for (int j = 0; j < 4; ++j) bb[j] = b1[tx * 4 + j];

    #pragma unroll
    for (int i = 0; i < 4; ++i) {
        int row = bm + ty * 4 + i;
        if (row < N_NODES) {
            float4 o;
            o.x = acc[i][0] + bb[0];
            o.y = acc[i][1] + bb[1];
            o.z = acc[i][2] + bb[2];
            o.w = acc[i][3] + bb[3];
            *(float4*)(h0 + (size_t)row * N_HID + tx * 4) = o;
        }
    }
}

// ---------------------------------------------------------------------------
// CSR build: count -> scan -> fill  (int atomics only)
// ---------------------------------------------------------------------------
__global__ __launch_bounds__(256) void count_k(const int* __restrict__ rowi,
                                               int* __restrict__ cnt) {
    int e = blockIdx.x * 256 + threadIdx.x;          // grid covers exactly N_EDGES
    atomicAdd(&cnt[rowi[e]], 1);
}

// blockwise exclusive scan of cnt -> rp (local), block totals -> blks
__global__ __launch_bounds__(256) void scan1_k(const int* __restrict__ cnt,
                                               int* __restrict__ rp,
                                               int* __restrict__ blks) {
    __shared__ int s[256];
    int i = blockIdx.x * 256 + threadIdx.x;
    int v = (i < N_NODES) ? cnt[i] : 0;
    s[threadIdx.x] = v;
    __syncthreads();
    #pragma unroll
    for (int off = 1; off < 256; off <<= 1) {
        int x = (threadIdx.x >= off) ? s[threadIdx.x - off] : 0;
        __syncthreads();
        s[threadIdx.x] += x;
        __syncthreads();
    }
    if (i < N_NODES) rp[i] = s[threadIdx.x] - v;     // exclusive, no block base
    if (threadIdx.x == 255) blks[blockIdx.x] = s[255];
}

// scan the 391 block totals (single block of 512)
__global__ __launch_bounds__(512) void scan2_k(int* __restrict__ blks, int nblk,
                                               int* __restrict__ rp) {
    __shared__ int s[512];
    int t = threadIdx.x;
    int v = (t < nblk) ? blks[t] : 0;
    s[t] = v;
    __syncthreads();
    #pragma unroll
    for (int off = 1; off < 512; off <<= 1) {
        int x = (t >= off) ? s[t - off] : 0;
        __syncthreads();
        s[t] += x;
        __syncthreads();
    }
    if (t < nblk) blks[t] = s[t] - v;                // exclusive block offsets
    if (t == 0) rp[N_NODES] = N_EDGES;
}

// add block offsets; snapshot cursor
__global__ __launch_bounds__(256) void scan3_k(int* __restrict__ rp,
                                               const int* __restrict__ blks,
                                               int* __restrict__ cur) {
    int i = blockIdx.x * 256 + threadIdx.x;
    if (i < N_NODES) {
        int p = rp[i] + blks[blockIdx.x];
        rp[i]  = p;
        cur[i] = p;
    }
}

__global__ __launch_bounds__(256) void fill_k(const int* __restrict__ rowi,
                                              const int* __restrict__ coli,
                                              const float* __restrict__ vals,
                                              int* __restrict__ cur,
                                              int* __restrict__ ecol,
                                              float* __restrict__ eval) {
    int e = blockIdx.x * 256 + threadIdx.x;          // grid covers exactly N_EDGES
    int p = atomicAdd(&cur[rowi[e]], 1);
    ecol[p] = coli[e];
    eval[p] = vals[e];
}

// ---------------------------------------------------------------------------
// SpMM1 (CSR): h1[row][0:64] = sum_e val[e] * h0[col[e]][0:64]
// One wave per row (lane = feature), 4 rows per block. No atomics.
// ---------------------------------------------------------------------------
__global__ __launch_bounds__(256) void spmm1_csr_k(const int* __restrict__ rp,
                                                   const int* __restrict__ ecol,
                                                   const float* __restrict__ eval,
                                                   const float* __restrict__ h0,
                                                   float* __restrict__ h1) {
    const int lane = threadIdx.x & 63;
    const int row  = __builtin_amdgcn_readfirstlane(blockIdx.x * 4 + (threadIdx.x >> 6));
    const int beg = rp[row];
    const int end = rp[row + 1];
    float acc = 0.f;
    int i = beg;
    for (; i + 4 <= end; i += 4) {
        int   c0 = ecol[i + 0], c1 = ecol[i + 1], c2 = ecol[i + 2], c3 = ecol[i + 3];
        float v0 = eval[i + 0], v1 = eval[i + 1], v2 = eval[i + 2], v3 = eval[i + 3];
        float g0 = h0[(size_t)c0 * N_HID + lane];
        float g1 = h0[(size_t)c1 * N_HID + lane];
        float g2 = h0[(size_t)c2 * N_HID + lane];
        float g3 = h0[(size_t)c3 * N_HID + lane];
        acc += v0 * g0;
        acc += v1 * g1;
        acc += v2 * g2;
        acc += v3 * g3;
    }
    for (; i < end; ++i)
        acc += eval[i] * h0[(size_t)ecol[i] * N_HID + lane];
    h1[(size_t)row * N_HID + lane] = acc;
}

// ---------------------------------------------------------------------------
// GEMM2 fused with ReLU: h2[100000][16] = relu(h1) @ W2 + b2
// ---------------------------------------------------------------------------
__global__ __launch_bounds__(256) void gemm2_k(const float* __restrict__ h1,
                                               const float* __restrict__ W2,
                                               const float* __restrict__ b2,
                                               float* __restrict__ h2) {
    __shared__ float Hs[64][65];
    __shared__ float Ws[64 * 16];
    __shared__ float bs[16];
    const int bn  = blockIdx.x * 64;
    const int tid = threadIdx.x;

    *(float4*)&Ws[tid * 4] = *(const float4*)(W2 + tid * 4);
    if (tid < 16) bs[tid] = b2[tid];

    #pragma unroll
    for (int i = 0; i < 4; ++i) {
        int idx  = tid + i * 256;
        int node = idx >> 4;
        int c4   = idx & 15;
        int nr   = bn + node;
        float4 hv = make_float4(0.f, 0.f, 0.f, 0.f);
        if (nr < N_NODES) hv = *(const float4*)(h1 + (size_t)nr * N_HID + c4 * 4);
        Hs[node][c4 * 4 + 0] = fmaxf(hv.x, 0.f);
        Hs[node][c4 * 4 + 1] = fmaxf(hv.y, 0.f);
        Hs[node][c4 * 4 + 2] = fmaxf(hv.z, 0.f);
        Hs[node][c4 * 4 + 3] = fmaxf(hv.w, 0.f);
    }
    __syncthreads();

    const int node = tid >> 2;
    const int c0   = (tid & 3) * 4;
    float a0 = bs[c0 + 0], a1 = bs[c0 + 1], a2 = bs[c0 + 2], a3 = bs[c0 + 3];
    #pragma unroll
    for (int k = 0; k < 64; ++k) {
        float hval = Hs[node][k];
        a0 += hval * Ws[k * 16 + c0 + 0];
        a1 += hval * Ws[k * 16 + c0 + 1];
        a2 += hval * Ws[k * 16 + c0 + 2];
        a3 += hval * Ws[k * 16 + c0 + 3];
    }
    int nr = bn + node;
    if (nr < N_NODES)
        *(float4*)(h2 + (size_t)nr * N_CLS + c0) = make_float4(a0, a1, a2, a3);
}

// ---------------------------------------------------------------------------
// SpMM2 (CSR) fused with log_softmax: 16 lanes per row, 16 rows per block.
// out[row][c] = spmm - logsumexp(spmm)   (cross-lane via shfl_xor width 16)
// ---------------------------------------------------------------------------
__global__ __launch_bounds__(256) void spmm2_lsm_k(const int* __restrict__ rp,
                                                   const int* __restrict__ ecol,
                                                   const float* __restrict__ eval,
                                                   const float* __restrict__ h2,
                                                   float* __restrict__ outp) {
    const int lane = threadIdx.x & 15;
    const int row  = blockIdx.x * 16 + (threadIdx.x >> 4);   // N_NODES = 6250*16 exact
    const int beg = rp[row];
    const int end = rp[row + 1];
    float acc = 0.f;
    int i = beg;
    for (; i + 2 <= end; i += 2) {
        int   c0 = ecol[i + 0], c1 = ecol[i + 1];
        float v0 = eval[i + 0], v1 = eval[i + 1];
        float g0 = h2[(size_t)c0 * N_CLS + lane];
        float g1 = h2[(size_t)c1 * N_CLS + lane];
        acc += v0 * g0;
        acc += v1 * g1;
    }
    if (i < end)
        acc += eval[i] * h2[(size_t)ecol[i] * N_CLS + lane];

    float m = acc;
    #pragma unroll
    for (int off = 8; off; off >>= 1) m = fmaxf(m, __shfl_xor(m, off, 16));
    float e = expf(acc - m);
    float s = e;
    #pragma unroll
    for (int off = 8; off; off >>= 1) s += __shfl_xor(s, off, 16);
    outp[(size_t)row * N_CLS + lane] = acc - m - logf(s);
}

extern "C" void kernel_launch(void* const* d_in, const int* in_sizes, int n_in,
                              void* d_out, int out_size, void* d_ws, size_t ws_size,
                              hipStream_t stream) {
    const float* x        = (const float*)d_in[0];
    const int*   adj_row  = (const int*)d_in[1];
    const int*   adj_col  = (const int*)d_in[2];
    const float* adj_vals = (const float*)d_in[3];
    const float* W1       = (const float*)d_in[4];
    const float* b1       = (const float*)d_in[5];
    const float* W2       = (const float*)d_in[6];
    const float* b2       = (const float*)d_in[7];
    float*       out      = (float*)d_out;

    // Workspace layout (peak ~65.8 MB):
    float* f    = (float*)d_ws;
    float* h0   = f;                                   // 6.40M floats (25.6 MB)
    float* h1   = h0 + (size_t)N_NODES * N_HID;        // 6.40M floats (25.6 MB)
    int*   ecol = (int*)(h1 + (size_t)N_NODES * N_HID);// 1.6M ints   (6.4 MB)
    float* eval = (float*)(ecol + N_EDGES);            // 1.6M floats (6.4 MB)
    int*   rp   = (int*)(eval + N_EDGES);              // 100001 ints
    int*   cur  = rp + (N_NODES + 2);                  // 100000 ints (doubles as counts)
    int*   blks = cur + N_NODES;                       // 512 ints
    float* h2   = h0;                                  // reuse (h0 dead after spmm1)

    const int NBLK_N = (N_NODES + 255) / 256;          // 391
    const int NBLK_E = N_EDGES / 256;                  // 6250 exact

    // --- CSR build (int atomics only) ---
    hipMemsetAsync(cur, 0, N_NODES * sizeof(int), stream);
    count_k<<<NBLK_E, 256, 0, stream>>>(adj_row, cur);
    scan1_k<<<NBLK_N, 256, 0, stream>>>(cur, rp, blks);
    scan2_k<<<1, 512, 0, stream>>>(blks, NBLK_N, rp);
    scan3_k<<<NBLK_N, 256, 0, stream>>>(rp, blks, cur);
    fill_k<<<NBLK_E, 256, 0, stream>>>(adj_row, adj_col, adj_vals, cur, ecol, eval);

    // --- layer 1 ---
    gemm1_k<<<(N_NODES + 63) / 64, 256, 0, stream>>>(x, W1, b1, h0);
    spmm1_csr_k<<<N_NODES / 4, 256, 0, stream>>>(rp, ecol, eval, h0, h1);

    // --- layer 2 (gemm2 reads h1, writes h2 == h0 region; then fused spmm+lsm) ---
    gemm2_k<<<(N_NODES + 63) / 64, 256, 0, stream>>>(h1, W2, b2, h2);
    spmm2_lsm_k<<<N_NODES / 16, 256, 0, stream>>>(rp, ecol, eval, h2, out);
}

// Round 6
// 458.436 us; speedup vs baseline: 4.0943x; 1.0288x over previous
//
#include <hip/hip_runtime.h>

#define N_NODES 100000
#define N_EDGES 1600000
#define N_FEAT  256
#define N_HID   64
#define N_CLS   16

typedef unsigned short bfraw;

__device__ __forceinline__ bfraw f2bf(float f) {   // RNE
    union { float f; unsigned int i; } v; v.f = f;
    unsigned int x = v.i;
    return (bfraw)((x + 0x7FFFu + ((x >> 16) & 1u)) >> 16);
}
__device__ __forceinline__ float bf2f(bfraw u) {
    union { unsigned int i; float f; } v; v.i = ((unsigned int)u) << 16; return v.f;
}

// ---------------------------------------------------------------------------
// GEMM1: h0[100000][64](bf16) = x[100000][256] @ W1[256][64] + b1
// 64x64 tile, 256 threads, 4x4 acc, BK=16. fp32 compute, bf16 store.
// ---------------------------------------------------------------------------
__global__ __launch_bounds__(256) void gemm1_k(const float* __restrict__ x,
                                               const float* __restrict__ W1,
                                               const float* __restrict__ b1,
                                               bfraw* __restrict__ h0) {
    __shared__ float As[16][64];   // [k][m]
    __shared__ float Bs[16][64];   // [k][n]
    const int bm  = blockIdx.x * 64;
    const int tid = threadIdx.x;
    const int tx = tid & 15;       // n/4
    const int ty = tid >> 4;       // m/4
    const int a_row = tid >> 2;
    const int a_k   = (tid & 3) * 4;
    const int b_k = tid >> 4;
    const int b_n = (tid & 15) * 4;

    const int  arow_g = bm + a_row;
    const bool a_ok   = arow_g < N_NODES;

    float acc[4][4] = {};

    for (int k0 = 0; k0 < N_FEAT; k0 += 16) {
        float4 ar = make_float4(0.f, 0.f, 0.f, 0.f);
        if (a_ok) ar = *(const float4*)(x + (size_t)arow_g * N_FEAT + k0 + a_k);
        float4 br = *(const float4*)(W1 + (size_t)(k0 + b_k) * N_HID + b_n);

        As[a_k + 0][a_row] = ar.x;
        As[a_k + 1][a_row] = ar.y;
        As[a_k + 2][a_row] = ar.z;
        As[a_k + 3][a_row] = ar.w;
        *(float4*)&Bs[b_k][b_n] = br;
        __syncthreads();

        #pragma unroll
        for (int kk = 0; kk < 16; ++kk) {
            float4 av = *(const float4*)&As[kk][ty * 4];
            float4 bv = *(const float4*)&Bs[kk][tx * 4];
            float a[4] = {av.x, av.y, av.z, av.w};
            float b[4] = {bv.x, bv.y, bv.z, bv.w};
            #pragma unroll
            for (int i = 0; i < 4; ++i)
                #pragma unroll
                for (int j = 0; j < 4; ++j)
                    acc[i][j] += a[i] * b[j];
        }
        __syncthreads();
    }

    float bb[4];
    #pragma unroll
    for (int j = 0; j < 4; ++j) bb[j] = b1[tx * 4 + j];

    #pragma unroll
    for (int i = 0; i < 4; ++i) {
        int row = bm + ty * 4 + i;
        if (row < N_NODES) {
            ushort4 o;
            o.x = f2bf(acc[i][0] + bb[0]);
            o.y = f2bf(acc[i][1] + bb[1]);
            o.z = f2bf(acc[i][2] + bb[2]);
            o.w = f2bf(acc[i][3] + bb[3]);
            *(ushort4*)(h0 + (size_t)row * N_HID + tx * 4) = o;
        }
    }
}

// ---------------------------------------------------------------------------
// CSR build: count -> scan -> fill  (int atomics only; AoS 8B edge records)
// ---------------------------------------------------------------------------
__global__ __launch_bounds__(256) void count_k(const int* __restrict__ rowi,
                                               int* __restrict__ cnt) {
    int e = blockIdx.x * 256 + threadIdx.x;          // grid covers exactly N_EDGES
    atomicAdd(&cnt[rowi[e]], 1);
}

__global__ __launch_bounds__(256) void scan1_k(const int* __restrict__ cnt,
                                               int* __restrict__ rp,
                                               int* __restrict__ blks) {
    __shared__ int s[256];
    int i = blockIdx.x * 256 + threadIdx.x;
    int v = (i < N_NODES) ? cnt[i] : 0;
    s[threadIdx.x] = v;
    __syncthreads();
    #pragma unroll
    for (int off = 1; off < 256; off <<= 1) {
        int x = (threadIdx.x >= off) ? s[threadIdx.x - off] : 0;
        __syncthreads();
        s[threadIdx.x] += x;
        __syncthreads();
    }
    if (i < N_NODES) rp[i] = s[threadIdx.x] - v;     // exclusive, no block base
    if (threadIdx.x == 255) blks[blockIdx.x] = s[255];
}

__global__ __launch_bounds__(512) void scan2_k(int* __restrict__ blks, int nblk,
                                               int* __restrict__ rp) {
    __shared__ int s[512];
    int t = threadIdx.x;
    int v = (t < nblk) ? blks[t] : 0;
    s[t] = v;
    __syncthreads();
    #pragma unroll
    for (int off = 1; off < 512; off <<= 1) {
        int x = (t >= off) ? s[t - off] : 0;
        __syncthreads();
        s[t] += x;
        __syncthreads();
    }
    if (t < nblk) blks[t] = s[t] - v;                // exclusive block offsets
    if (t == 0) rp[N_NODES] = N_EDGES;
}

__global__ __launch_bounds__(256) void scan3_k(int* __restrict__ rp,
                                               const int* __restrict__ blks,
                                               int* __restrict__ cur) {
    int i = blockIdx.x * 256 + threadIdx.x;
    if (i < N_NODES) {
        int p = rp[i] + blks[blockIdx.x];
        rp[i]  = p;
        cur[i] = p;
    }
}

__global__ __launch_bounds__(256) void fill_k(const int* __restrict__ rowi,
                                              const int* __restrict__ coli,
                                              const float* __restrict__ vals,
                                              int* __restrict__ cur,
                                              int2* __restrict__ edges) {
    int e = blockIdx.x * 256 + threadIdx.x;          // grid covers exactly N_EDGES
    int p = atomicAdd(&cur[rowi[e]], 1);
    edges[p] = make_int2(coli[e], __float_as_int(vals[e]));
}

// ---------------------------------------------------------------------------
// SpMM1 (CSR): h1[row][0:64](fp32) = sum_e val[e] * h0[col[e]][0:64](bf16)
// One wave per row (lane = feature), 4 rows per block. No atomics.
// ---------------------------------------------------------------------------
__global__ __launch_bounds__(256) void spmm1_csr_k(const int* __restrict__ rp,
                                                   const int2* __restrict__ edges,
                                                   const bfraw* __restrict__ h0,
                                                   float* __restrict__ h1) {
    const int lane = threadIdx.x & 63;
    const int row  = __builtin_amdgcn_readfirstlane(blockIdx.x * 4 + (threadIdx.x >> 6));
    const int beg = rp[row];
    const int end = rp[row + 1];
    float acc = 0.f;
    int i = beg;
    for (; i + 4 <= end; i += 4) {
        int2 e0 = edges[i + 0], e1 = edges[i + 1], e2 = edges[i + 2], e3 = edges[i + 3];
        float g0 = bf2f(h0[(size_t)e0.x * N_HID + lane]);
        float g1 = bf2f(h0[(size_t)e1.x * N_HID + lane]);
        float g2 = bf2f(h0[(size_t)e2.x * N_HID + lane]);
        float g3 = bf2f(h0[(size_t)e3.x * N_HID + lane]);
        acc += __int_as_float(e0.y) * g0;
        acc += __int_as_float(e1.y) * g1;
        acc += __int_as_float(e2.y) * g2;
        acc += __int_as_float(e3.y) * g3;
    }
    for (; i < end; ++i) {
        int2 e = edges[i];
        acc += __int_as_float(e.y) * bf2f(h0[(size_t)e.x * N_HID + lane]);
    }
    h1[(size_t)row * N_HID + lane] = acc;
}

// ---------------------------------------------------------------------------
// GEMM2 fused with ReLU: h2[100000][16] = relu(h1) @ W2 + b2   (fp32)
// ---------------------------------------------------------------------------
__global__ __launch_bounds__(256) void gemm2_k(const float* __restrict__ h1,
                                               const float* __restrict__ W2,
                                               const float* __restrict__ b2,
                                               float* __restrict__ h2) {
    __shared__ float Hs[64][65];
    __shared__ float Ws[64 * 16];
    __shared__ float bs[16];
    const int bn  = blockIdx.x * 64;
    const int tid = threadIdx.x;

    *(float4*)&Ws[tid * 4] = *(const float4*)(W2 + tid * 4);
    if (tid < 16) bs[tid] = b2[tid];

    #pragma unroll
    for (int i = 0; i < 4; ++i) {
        int idx  = tid + i * 256;
        int node = idx >> 4;
        int c4   = idx & 15;
        int nr   = bn + node;
        float4 hv = make_float4(0.f, 0.f, 0.f, 0.f);
        if (nr < N_NODES) hv = *(const float4*)(h1 + (size_t)nr * N_HID + c4 * 4);
        Hs[node][c4 * 4 + 0] = fmaxf(hv.x, 0.f);
        Hs[node][c4 * 4 + 1] = fmaxf(hv.y, 0.f);
        Hs[node][c4 * 4 + 2] = fmaxf(hv.z, 0.f);
        Hs[node][c4 * 4 + 3] = fmaxf(hv.w, 0.f);
    }
    __syncthreads();

    const int node = tid >> 2;
    const int c0   = (tid & 3) * 4;
    float a0 = bs[c0 + 0], a1 = bs[c0 + 1], a2 = bs[c0 + 2], a3 = bs[c0 + 3];
    #pragma unroll
    for (int k = 0; k < 64; ++k) {
        float hval = Hs[node][k];
        a0 += hval * Ws[k * 16 + c0 + 0];
        a1 += hval * Ws[k * 16 + c0 + 1];
        a2 += hval * Ws[k * 16 + c0 + 2];
        a3 += hval * Ws[k * 16 + c0 + 3];
    }
    int nr = bn + node;
    if (nr < N_NODES)
        *(float4*)(h2 + (size_t)nr * N_CLS + c0) = make_float4(a0, a1, a2, a3);
}

// ---------------------------------------------------------------------------
// SpMM2 (CSR) fused with log_softmax: 16 lanes per row, 16 rows per block.
// ---------------------------------------------------------------------------
__global__ __launch_bounds__(256) void spmm2_lsm_k(const int* __restrict__ rp,
                                                   const int2* __restrict__ edges,
                                                   const float* __restrict__ h2,
                                                   float* __restrict__ outp) {
    const int lane = threadIdx.x & 15;
    const int row  = blockIdx.x * 16 + (threadIdx.x >> 4);   // N_NODES = 6250*16 exact
    const int beg = rp[row];
    const int end = rp[row + 1];
    float acc = 0.f;
    int i = beg;
    for (; i + 2 <= end; i += 2) {
        int2 e0 = edges[i + 0], e1 = edges[i + 1];
        float g0 = h2[(size_t)e0.x * N_CLS + lane];
        float g1 = h2[(size_t)e1.x * N_CLS + lane];
        acc += __int_as_float(e0.y) * g0;
        acc += __int_as_float(e1.y) * g1;
    }
    if (i < end) {
        int2 e = edges[i];
        acc += __int_as_float(e.y) * h2[(size_t)e.x * N_CLS + lane];
    }

    float m = acc;
    #pragma unroll
    for (int off = 8; off; off >>= 1) m = fmaxf(m, __shfl_xor(m, off, 16));
    float ex = expf(acc - m);
    float s = ex;
    #pragma unroll
    for (int off = 8; off; off >>= 1) s += __shfl_xor(s, off, 16);
    outp[(size_t)row * N_CLS + lane] = acc - m - logf(s);
}

extern "C" void kernel_launch(void* const* d_in, const int* in_sizes, int n_in,
                              void* d_out, int out_size, void* d_ws, size_t ws_size,
                              hipStream_t stream) {
    const float* x        = (const float*)d_in[0];
    const int*   adj_row  = (const int*)d_in[1];
    const int*   adj_col  = (const int*)d_in[2];
    const float* adj_vals = (const float*)d_in[3];
    const float* W1       = (const float*)d_in[4];
    const float* b1       = (const float*)d_in[5];
    const float* W2       = (const float*)d_in[6];
    const float* b2       = (const float*)d_in[7];
    float*       out      = (float*)d_out;

    // Workspace layout (peak ~52 MB):
    const size_t H0_BYTES = (size_t)N_NODES * N_HID * sizeof(bfraw);   // 12.8 MB
    const size_t H1_BYTES = (size_t)N_NODES * N_HID * sizeof(float);   // 25.6 MB
    const size_t E_BYTES  = (size_t)N_EDGES * sizeof(int2);            // 12.8 MB
    bfraw* h0    = (bfraw*)d_ws;
    float* h1    = (float*)((char*)d_ws + H0_BYTES);
    int2*  edges = (int2*)((char*)h1 + H1_BYTES);
    int*   rp    = (int*)((char*)edges + E_BYTES);     // 100001 ints
    int*   cur   = rp + (N_NODES + 2);                 // 100000 ints
    int*   blks  = cur + N_NODES;                      // 512 ints
    float* h2    = (float*)d_ws;                       // reuse h0 region (6.4 MB)

    const int NBLK_N = (N_NODES + 255) / 256;          // 391
    const int NBLK_E = N_EDGES / 256;                  // 6250 exact

    // --- CSR build ---
    hipMemsetAsync(cur, 0, N_NODES * sizeof(int), stream);
    count_k<<<NBLK_E, 256, 0, stream>>>(adj_row, cur);
    scan1_k<<<NBLK_N, 256, 0, stream>>>(cur, rp, blks);
    scan2_k<<<1, 512, 0, stream>>>(blks, NBLK_N, rp);
    scan3_k<<<NBLK_N, 256, 0, stream>>>(rp, blks, cur);
    fill_k<<<NBLK_E, 256, 0, stream>>>(adj_row, adj_col, adj_vals, cur, edges);

    // --- layer 1 ---
    gemm1_k<<<(N_NODES + 63) / 64, 256, 0, stream>>>(x, W1, b1, h0);
    spmm1_csr_k<<<N_NODES / 4, 256, 0, stream>>>(rp, edges, h0, h1);

    // --- layer 2 ---
    gemm2_k<<<(N_NODES + 63) / 64, 256, 0, stream>>>(h1, W2, b2, h2);
    spmm2_lsm_k<<<N_NODES / 16, 256, 0, stream>>>(rp, edges, h2, out);
}